// Round 4
// baseline (1083.824 us; speedup 1.0000x reference)
//
#include <hip/hip_runtime.h>
#include <stdint.h>

// NodeModel: edge MLP (Lin 128->64 + BN(batch stats) + SiLU) -> scatter_mean -> node MLP.
// f32 inputs/outputs, int32 edge_index. MFMA in bf16 (RNE), f32 accumulate.
//
// FAST path (ws >= ~150 MB): CSR-gather design, no scatter atomics:
//   hist -> scan -> fill (CSR of incoming edges per node)
//   edge GEMM once: column stats + h1 bf16 materialization
//   agg: per-node wave gathers h1 rows, norm+SiLU, mean  (no atomics)
//   node GEMM x2 (stats, out) reading [x | agg]
// FALLBACK (small ws): R3's 4-pass recompute pipeline (proven, 979 us).

#define EPS 1e-5f

using short8  = __attribute__((ext_vector_type(8))) short;
using floatx4 = __attribute__((ext_vector_type(4))) float;

__device__ __forceinline__ ushort f2bf(float f) {
  uint32_t u = __builtin_bit_cast(uint32_t, f);
  u += 0x7fffu + ((u >> 16) & 1u);   // RNE
  return (ushort)(u >> 16);
}
__device__ __forceinline__ float bf2f(ushort h) {
  uint32_t u = ((uint32_t)h) << 16;
  return __builtin_bit_cast(float, u);
}
__device__ __forceinline__ float silu(float v) {
  return v / (1.0f + __expf(-v));
}
__device__ __forceinline__ void pack4(ushort* dst, float4 v) {
  uint2 p;
  p.x = (uint)f2bf(v.x) | ((uint)f2bf(v.y) << 16);
  p.y = (uint)f2bf(v.z) | ((uint)f2bf(v.w) << 16);
  *(uint2*)dst = p;
}

// ---------------------------------------------------------------- fast path

__global__ __launch_bounds__(256) void hist_k(const int* __restrict__ col,
                                              int* __restrict__ deg, int E) {
  const int e = blockIdx.x * 256 + threadIdx.x;
  if (e < E) atomicAdd(&deg[col[e]], 1);
}

// single-block exclusive scan of deg -> rowptr[0..N], cursor copy
__global__ __launch_bounds__(256) void scan_deg(const int* __restrict__ deg,
                                                int* __restrict__ rowptr,
                                                int* __restrict__ cursor, int N) {
  __shared__ int psum[256];
  __shared__ int carry;
  const int tid = threadIdx.x;
  if (tid == 0) carry = 0;
  __syncthreads();
  for (int base = 0; base < N; base += 4096) {
    const int i0 = base + tid * 16;
    int excl[16];
    int s = 0;
#pragma unroll
    for (int j = 0; j < 16; ++j) {
      const int idx = i0 + j;
      const int v = (idx < N) ? deg[idx] : 0;
      excl[j] = s;
      s += v;
    }
    psum[tid] = s;
    __syncthreads();
    for (int off = 1; off < 256; off <<= 1) {
      const int t = (tid >= off) ? psum[tid - off] : 0;
      __syncthreads();
      psum[tid] += t;
      __syncthreads();
    }
    const int texcl = carry + (tid ? psum[tid - 1] : 0);
    const int total = psum[255];
#pragma unroll
    for (int j = 0; j < 16; ++j) {
      const int idx = i0 + j;
      if (idx < N) {
        const int rp = texcl + excl[j];
        rowptr[idx] = rp;
        cursor[idx] = rp;
      }
    }
    __syncthreads();
    if (tid == 0) carry += total;
    __syncthreads();
  }
  if (tid == 0) rowptr[N] = carry;
}

__global__ __launch_bounds__(256) void fill_k(const int* __restrict__ col,
                                              int* __restrict__ cursor,
                                              int* __restrict__ eidx, int E) {
  const int e = blockIdx.x * 256 + threadIdx.x;
  if (e < E) {
    const int pos = atomicAdd(&cursor[col[e]], 1);
    eidx[pos] = e;
  }
}

// Edge GEMM: [x[row]|ea] @ W1 + b1 -> h1 (bf16) + column sum/sumsq
__global__ __launch_bounds__(256) void edge_gemm_stats(
    const float* __restrict__ x, const float* __restrict__ ea,
    const int* __restrict__ rowidx,
    const float* __restrict__ W, const float* __restrict__ bias,
    float* __restrict__ ssum, float* __restrict__ ssq,
    ushort* __restrict__ h1, int nrows, int ntiles) {
  __shared__ __align__(16) ushort Albs[64 * 136];
  __shared__ __align__(16) ushort Btl[64 * 136];
  __shared__ float wsum[4][64];
  __shared__ float wsq[4][64];
  __shared__ float biasl[64];

  const int tid  = threadIdx.x;
  const int lane = tid & 63;
  const int wv   = tid >> 6;
  const int m    = lane & 15;
  const int quad = lane >> 4;

  for (int i = tid; i < 64 * 128; i += 256) {
    const int n = i >> 7, k = i & 127;
    Btl[n * 136 + k] = f2bf(W[k * 64 + n]);
  }
  if (tid < 64) biasl[tid] = bias[tid];
  wsum[wv][lane] = 0.f;
  wsq[wv][lane]  = 0.f;

  for (int t = blockIdx.x; t < ntiles; t += gridDim.x) {
    __syncthreads();
    const int base = t * 64;
    for (int i = tid; i < 2048; i += 256) {
      const int e  = i >> 5;
      const int c4 = (i & 31) << 2;
      const int grow = base + e;
      float4 v = make_float4(0.f, 0.f, 0.f, 0.f);
      if (grow < nrows) {
        if (c4 < 64) {
          const int r = rowidx[grow];
          v = *(const float4*)(x + (size_t)r * 64 + c4);
        } else {
          v = *(const float4*)(ea + (size_t)grow * 64 + (c4 - 64));
        }
      }
      pack4(&Albs[e * 136 + c4], v);
    }
    __syncthreads();

    floatx4 acc[4];
#pragma unroll
    for (int nt = 0; nt < 4; ++nt) acc[nt] = (floatx4){0.f, 0.f, 0.f, 0.f};
    const ushort* arow = &Albs[(wv * 16 + m) * 136];
#pragma unroll
    for (int kc = 0; kc < 4; ++kc) {
      const short8 af = *(const short8*)(arow + kc * 32 + quad * 8);
#pragma unroll
      for (int nt = 0; nt < 4; ++nt) {
        const short8 bfr = *(const short8*)(&Btl[(nt * 16 + m) * 136 + kc * 32 + quad * 8]);
        acc[nt] = __builtin_amdgcn_mfma_f32_16x16x32_bf16(af, bfr, acc[nt], 0, 0, 0);
      }
    }

    const int lr0 = wv * 16 + quad * 4;
#pragma unroll
    for (int nt = 0; nt < 4; ++nt) {
      const int c = nt * 16 + m;
      const float bb = biasl[c];
      float s = 0.f, q = 0.f;
#pragma unroll
      for (int r = 0; r < 4; ++r) {
        const int grow = base + lr0 + r;
        if (grow < nrows) {
          const float v = acc[nt][r] + bb;
          s += v;
          q += v * v;
          h1[(size_t)grow * 64 + c] = f2bf(v);
        }
      }
      s += __shfl_xor(s, 16); s += __shfl_xor(s, 32);
      q += __shfl_xor(q, 16); q += __shfl_xor(q, 32);
      if (quad == 0) { wsum[wv][c] += s; wsq[wv][c] += q; }
    }
  }
  __syncthreads();
  if (tid < 128) {
    const int c = tid & 63;
    if (tid < 64) {
      unsafeAtomicAdd(&ssum[c], wsum[0][c] + wsum[1][c] + wsum[2][c] + wsum[3][c]);
    } else {
      unsafeAtomicAdd(&ssq[c], wsq[0][c] + wsq[1][c] + wsq[2][c] + wsq[3][c]);
    }
  }
}

// one wave per node: lane = col. agg[n][c] = mean_e silu(norm(h1[e][c]))
__global__ __launch_bounds__(256) void agg_k(
    const ushort* __restrict__ h1, const int* __restrict__ rowptr,
    const int* __restrict__ eidx, const float* __restrict__ scsh,
    ushort* __restrict__ agg, int N) {
  __shared__ float scl[128];
  const int tid = threadIdx.x;
  if (tid < 128) scl[tid] = scsh[tid];
  __syncthreads();
  const int n = blockIdx.x * 4 + (tid >> 6);
  const int c = tid & 63;
  if (n >= N) return;
  const int b = rowptr[n], e = rowptr[n + 1];
  const float sc = scl[c], sh = scl[64 + c];
  float acc = 0.f;
  for (int j = b; j < e; ++j) {
    const int ed = eidx[j];
    acc += silu(bf2f(h1[(size_t)ed * 64 + c]) * sc + sh);
  }
  agg[(size_t)n * 64 + c] = f2bf(acc / fmaxf((float)(e - b), 1.f));
}

// Node GEMM: [x | agg] @ W2 + b2.  STATS=1: column stats; else norm+SiLU -> out
template <bool STATS>
__global__ __launch_bounds__(256) void node_gemm(
    const float* __restrict__ x, const ushort* __restrict__ agg,
    const float* __restrict__ W, const float* __restrict__ bias,
    const float* __restrict__ scsh,
    float* __restrict__ ssum, float* __restrict__ ssq,
    float* __restrict__ out, int nrows, int ntiles) {
  __shared__ __align__(16) ushort Albs[64 * 136];
  __shared__ __align__(16) ushort Btl[64 * 136];
  __shared__ float wsum[4][64];
  __shared__ float wsq[4][64];
  __shared__ float biasl[64];
  __shared__ float scl[128];

  const int tid  = threadIdx.x;
  const int lane = tid & 63;
  const int wv   = tid >> 6;
  const int m    = lane & 15;
  const int quad = lane >> 4;

  for (int i = tid; i < 64 * 128; i += 256) {
    const int n = i >> 7, k = i & 127;
    Btl[n * 136 + k] = f2bf(W[k * 64 + n]);
  }
  if (tid < 64) biasl[tid] = bias[tid];
  if (!STATS) {
    if (tid < 128) scl[tid] = scsh[tid];
  } else {
    wsum[wv][lane] = 0.f;
    wsq[wv][lane]  = 0.f;
  }

  for (int t = blockIdx.x; t < ntiles; t += gridDim.x) {
    __syncthreads();
    const int base = t * 64;
    for (int i = tid; i < 2048; i += 256) {
      const int e  = i >> 5;
      const int c4 = (i & 31) << 2;
      const int grow = base + e;
      if (grow < nrows) {
        if (c4 < 64) {
          pack4(&Albs[e * 136 + c4], *(const float4*)(x + (size_t)grow * 64 + c4));
        } else {
          *(uint2*)&Albs[e * 136 + c4] =
              *(const uint2*)(agg + (size_t)grow * 64 + (c4 - 64));
        }
      } else {
        *(uint2*)&Albs[e * 136 + c4] = make_uint2(0u, 0u);
      }
    }
    __syncthreads();

    floatx4 acc[4];
#pragma unroll
    for (int nt = 0; nt < 4; ++nt) acc[nt] = (floatx4){0.f, 0.f, 0.f, 0.f};
    const ushort* arow = &Albs[(wv * 16 + m) * 136];
#pragma unroll
    for (int kc = 0; kc < 4; ++kc) {
      const short8 af = *(const short8*)(arow + kc * 32 + quad * 8);
#pragma unroll
      for (int nt = 0; nt < 4; ++nt) {
        const short8 bfr = *(const short8*)(&Btl[(nt * 16 + m) * 136 + kc * 32 + quad * 8]);
        acc[nt] = __builtin_amdgcn_mfma_f32_16x16x32_bf16(af, bfr, acc[nt], 0, 0, 0);
      }
    }

    const int lr0 = wv * 16 + quad * 4;
#pragma unroll
    for (int nt = 0; nt < 4; ++nt) {
      const int c = nt * 16 + m;
      const float bb = biasl[c];
      if (STATS) {
        float s = 0.f, q = 0.f;
#pragma unroll
        for (int r = 0; r < 4; ++r) {
          const int grow = base + lr0 + r;
          if (grow < nrows) {
            const float v = acc[nt][r] + bb;
            s += v;
            q += v * v;
          }
        }
        s += __shfl_xor(s, 16); s += __shfl_xor(s, 32);
        q += __shfl_xor(q, 16); q += __shfl_xor(q, 32);
        if (quad == 0) { wsum[wv][c] += s; wsq[wv][c] += q; }
      } else {
        const float sc = scl[c];
        const float sh = scl[64 + c];
#pragma unroll
        for (int r = 0; r < 4; ++r) {
          const int grow = base + lr0 + r;
          if (grow < nrows) {
            out[(size_t)grow * 64 + c] = silu((acc[nt][r] + bb) * sc + sh);
          }
        }
      }
    }
  }

  if (STATS) {
    __syncthreads();
    if (tid < 128) {
      const int c = tid & 63;
      if (tid < 64) {
        unsafeAtomicAdd(&ssum[c], wsum[0][c] + wsum[1][c] + wsum[2][c] + wsum[3][c]);
      } else {
        unsafeAtomicAdd(&ssq[c], wsq[0][c] + wsq[1][c] + wsq[2][c] + wsq[3][c]);
      }
    }
  }
}

__global__ void finalize_stats(const float* __restrict__ ss, const float* __restrict__ sq,
                               const float* __restrict__ g, const float* __restrict__ be,
                               float* __restrict__ scsh, float invn) {
  const int c = threadIdx.x;  // 64 threads
  const float mu  = ss[c] * invn;
  const float var = sq[c] * invn - mu * mu;
  const float rs  = rsqrtf(fmaxf(var, 0.0f) + EPS);
  const float s   = g[c] * rs;
  scsh[c]      = s;
  scsh[64 + c] = be[c] - mu * s;
}

// ------------------------------------------------------------ fallback (R3)

template <int MODE>
__global__ __launch_bounds__(256) void fused_gemm(
    const float* __restrict__ x, const float* __restrict__ ea,
    const float* __restrict__ sums_in, const float* __restrict__ cnt,
    const int* __restrict__ rowidx, const int* __restrict__ colidx,
    const float* __restrict__ W, const float* __restrict__ bias,
    const float* __restrict__ scsh,
    float* __restrict__ ssum, float* __restrict__ ssq,
    float* __restrict__ sums_out, float* __restrict__ cnt_out,
    float* __restrict__ out,
    int nrows, int ntiles) {
  __shared__ __align__(16) ushort Albs[64 * 136];
  __shared__ __align__(16) ushort Btl[64 * 136];
  __shared__ float wsum[4][64];
  __shared__ float wsq[4][64];
  __shared__ float biasl[64];
  __shared__ float scl[128];
  __shared__ int coltile[64];

  const int tid  = threadIdx.x;
  const int lane = tid & 63;
  const int wv   = tid >> 6;
  const int m    = lane & 15;
  const int quad = lane >> 4;

  for (int i = tid; i < 64 * 128; i += 256) {
    const int n = i >> 7, k = i & 127;
    Btl[n * 136 + k] = f2bf(W[k * 64 + n]);
  }
  if (tid < 64) biasl[tid] = bias[tid];
  if (MODE == 1 || MODE == 3) {
    if (tid < 128) scl[tid] = scsh[tid];
  }
  if (MODE == 0 || MODE == 2) {
    wsum[wv][lane] = 0.f;
    wsq[wv][lane]  = 0.f;
  }

  for (int t = blockIdx.x; t < ntiles; t += gridDim.x) {
    __syncthreads();
    const int base = t * 64;
    for (int i = tid; i < 2048; i += 256) {
      const int e  = i >> 5;
      const int c4 = (i & 31) << 2;
      const int grow = base + e;
      float4 v = make_float4(0.f, 0.f, 0.f, 0.f);
      if (grow < nrows) {
        if (MODE <= 1) {
          if (c4 < 64) {
            const int r = rowidx[grow];
            v = *(const float4*)(x + (size_t)r * 64 + c4);
          } else {
            v = *(const float4*)(ea + (size_t)grow * 64 + (c4 - 64));
          }
          if (MODE == 1 && c4 == 0) coltile[e] = colidx[grow];
        } else {
          if (c4 < 64) {
            v = *(const float4*)(x + (size_t)grow * 64 + c4);
          } else {
            const float inv = 1.0f / fmaxf(cnt[grow], 1.0f);
            v = *(const float4*)(sums_in + (size_t)grow * 64 + (c4 - 64));
            v.x *= inv; v.y *= inv; v.z *= inv; v.w *= inv;
          }
        }
      }
      pack4(&Albs[e * 136 + c4], v);
    }
    __syncthreads();

    floatx4 acc[4];
#pragma unroll
    for (int nt = 0; nt < 4; ++nt) acc[nt] = (floatx4){0.f, 0.f, 0.f, 0.f};
    const ushort* arow = &Albs[(wv * 16 + m) * 136];
#pragma unroll
    for (int kc = 0; kc < 4; ++kc) {
      const short8 af = *(const short8*)(arow + kc * 32 + quad * 8);
#pragma unroll
      for (int nt = 0; nt < 4; ++nt) {
        const short8 bfr = *(const short8*)(&Btl[(nt * 16 + m) * 136 + kc * 32 + quad * 8]);
        acc[nt] = __builtin_amdgcn_mfma_f32_16x16x32_bf16(af, bfr, acc[nt], 0, 0, 0);
      }
    }

    const int lr0 = wv * 16 + quad * 4;
#pragma unroll
    for (int nt = 0; nt < 4; ++nt) {
      const int c = nt * 16 + m;
      const float bb = biasl[c];
      if (MODE == 0 || MODE == 2) {
        float s = 0.f, q = 0.f;
#pragma unroll
        for (int r = 0; r < 4; ++r) {
          const int grow = base + lr0 + r;
          if (grow < nrows) {
            const float v = acc[nt][r] + bb;
            s += v;
            q += v * v;
          }
        }
        s += __shfl_xor(s, 16); s += __shfl_xor(s, 32);
        q += __shfl_xor(q, 16); q += __shfl_xor(q, 32);
        if (quad == 0) { wsum[wv][c] += s; wsq[wv][c] += q; }
      } else {
        const float sc = scl[c];
        const float sh = scl[64 + c];
#pragma unroll
        for (int r = 0; r < 4; ++r) {
          const int e = lr0 + r;
          const int grow = base + e;
          if (grow < nrows) {
            const float o = silu((acc[nt][r] + bb) * sc + sh);
            if (MODE == 1) {
              unsafeAtomicAdd(&sums_out[(size_t)coltile[e] * 64 + c], o);
            } else {
              out[(size_t)grow * 64 + c] = o;
            }
          }
        }
        if (MODE == 1 && nt == 0 && m == 0) {
#pragma unroll
          for (int r = 0; r < 4; ++r) {
            const int e = lr0 + r;
            if (base + e < nrows) unsafeAtomicAdd(&cnt_out[coltile[e]], 1.0f);
          }
        }
      }
    }
  }

  if (MODE == 0 || MODE == 2) {
    __syncthreads();
    if (tid < 128) {
      const int c = tid & 63;
      if (tid < 64) {
        unsafeAtomicAdd(&ssum[c], wsum[0][c] + wsum[1][c] + wsum[2][c] + wsum[3][c]);
      } else {
        unsafeAtomicAdd(&ssq[c], wsq[0][c] + wsq[1][c] + wsq[2][c] + wsq[3][c]);
      }
    }
  }
}

// -------------------------------------------------------------------- launch

extern "C" void kernel_launch(void* const* d_in, const int* in_sizes, int n_in,
                              void* d_out, int out_size, void* d_ws, size_t ws_size,
                              hipStream_t stream) {
  const int N = in_sizes[0] / 64;
  const int E = in_sizes[1] / 64;
  const float* x   = (const float*)d_in[0];
  const float* ea  = (const float*)d_in[1];
  const float* W1  = (const float*)d_in[3];
  const float* b1  = (const float*)d_in[4];
  const float* g1  = (const float*)d_in[5];
  const float* be1 = (const float*)d_in[6];
  const float* W2  = (const float*)d_in[7];
  const float* b2  = (const float*)d_in[8];
  const float* g2  = (const float*)d_in[9];
  const float* be2 = (const float*)d_in[10];
  const int* ei   = (const int*)d_in[11];  // [2,E] int32
  const int* row  = ei;
  const int* colv = ei + E;

  const int ntE = (E + 63) / 64;
  const int ntN = (N + 63) / 64;
  const int gE  = ntE < 2048 ? ntE : 2048;
  const int gN  = ntN < 2048 ? ntN : 2048;

  // fast-path workspace layout
  float* stats  = (float*)d_ws;                  // statE|statN|scsh1|scsh2 = 512 f32
  float* statE  = stats;
  float* statN  = stats + 128;
  float* scsh1  = stats + 256;
  float* scsh2  = stats + 384;
  int*   deg    = (int*)(stats + 512);           // N
  int*   rowptr = deg + N;                       // N+1
  int*   cursor = rowptr + N + 1;                // N
  int*   eidx   = cursor + N;                    // E
  ushort* agg   = (ushort*)(eidx + E);           // N*64
  ushort* h1    = agg + (size_t)N * 64;          // E*64
  const size_t need_fast =
      (char*)(h1 + (size_t)E * 64) - (char*)d_ws;

  if (ws_size >= need_fast) {
    // zero stats + deg (rowptr/cursor/eidx fully overwritten downstream)
    hipMemsetAsync(d_ws, 0, 512 * sizeof(float) + (size_t)N * sizeof(int), stream);

    hist_k<<<dim3((E + 255) / 256), dim3(256), 0, stream>>>(colv, deg, E);
    scan_deg<<<dim3(1), dim3(256), 0, stream>>>(deg, rowptr, cursor, N);
    fill_k<<<dim3((E + 255) / 256), dim3(256), 0, stream>>>(colv, cursor, eidx, E);

    edge_gemm_stats<<<dim3(gE), dim3(256), 0, stream>>>(
        x, ea, row, W1, b1, statE, statE + 64, h1, E, ntE);
    finalize_stats<<<dim3(1), dim3(64), 0, stream>>>(statE, statE + 64, g1, be1, scsh1,
                                                     1.0f / (float)E);
    agg_k<<<dim3((N + 3) / 4), dim3(256), 0, stream>>>(h1, rowptr, eidx, scsh1, agg, N);

    node_gemm<true><<<dim3(gN), dim3(256), 0, stream>>>(
        x, agg, W2, b2, nullptr, statN, statN + 64, nullptr, N, ntN);
    finalize_stats<<<dim3(1), dim3(64), 0, stream>>>(statN, statN + 64, g2, be2, scsh2,
                                                     1.0f / (float)N);
    node_gemm<false><<<dim3(gN), dim3(256), 0, stream>>>(
        x, agg, W2, b2, scsh2, nullptr, nullptr, (float*)d_out, N, ntN);
  } else {
    // ---- fallback: R3 recompute pipeline (~26 MB ws) ----
    float* sums   = (float*)d_ws;          // N*64
    float* cntf   = sums + (size_t)N * 64; // N
    float* statEf = cntf + N;              // 128
    float* statNf = statEf + 128;          // 128
    float* scsh1f = statNf + 128;          // 128
    float* scsh2f = scsh1f + 128;          // 128

    hipMemsetAsync(d_ws, 0, ((size_t)N * 65 + 512) * sizeof(float), stream);

    fused_gemm<0><<<dim3(gE), dim3(256), 0, stream>>>(
        x, ea, nullptr, nullptr, row, nullptr, W1, b1, nullptr,
        statEf, statEf + 64, nullptr, nullptr, nullptr, E, ntE);
    finalize_stats<<<dim3(1), dim3(64), 0, stream>>>(statEf, statEf + 64, g1, be1,
                                                     scsh1f, 1.0f / (float)E);
    fused_gemm<1><<<dim3(gE), dim3(256), 0, stream>>>(
        x, ea, nullptr, nullptr, row, colv, W1, b1, scsh1f,
        nullptr, nullptr, sums, cntf, nullptr, E, ntE);
    fused_gemm<2><<<dim3(gN), dim3(256), 0, stream>>>(
        x, nullptr, sums, cntf, nullptr, nullptr, W2, b2, nullptr,
        statNf, statNf + 64, nullptr, nullptr, nullptr, N, ntN);
    finalize_stats<<<dim3(1), dim3(64), 0, stream>>>(statNf, statNf + 64, g2, be2,
                                                     scsh2f, 1.0f / (float)N);
    fused_gemm<3><<<dim3(gN), dim3(256), 0, stream>>>(
        x, nullptr, sums, cntf, nullptr, nullptr, W2, b2, scsh2f,
        nullptr, nullptr, nullptr, nullptr, (float*)d_out, N, ntN);
  }
}